// Round 1
// baseline (1324.547 us; speedup 1.0000x reference)
//
#include <hip/hip_runtime.h>

typedef _Float16 half8 __attribute__((ext_vector_type(8)));
typedef _Float16 half4 __attribute__((ext_vector_type(4)));
typedef float    f32x4v __attribute__((ext_vector_type(4)));

constexpr int S    = 2048;   // sequence length
constexpr int D    = 128;    // hidden dim
constexpr int TQ   = 32;     // q rows per block
constexpr int QB   = S / TQ; // 64 q-blocks per batch
constexpr int CPW  = 256;    // score cols per col-wave-group (8 groups)
constexpr int NT   = CPW / 16;  // 16 col tiles per wave
constexpr int PPAD = 8;         // half-elements pad: row stride 528B (16B aligned, conflict-free b128 reads)
constexpr float SCALE = 0.08838834764831845f; // 1/sqrt(128)

// 16 waves = 2 q-row groups (wr) x 8 col groups (wc).
// 16x16x32 f16 MFMA. C/D layout (m89): col = lane&15, row = (lane>>4)*4 + reg.
// A[m=lane&15][k=(lane>>4)*8+j], B[k=(lane>>4)*8+j][n=lane&15].
__launch_bounds__(1024, 4)
__global__ void attn_fwd(const float* __restrict__ Q,
                         const float* __restrict__ K,
                         const float* __restrict__ V,
                         float* __restrict__ Oc,
                         float* __restrict__ Oa)
{
    // ---- XCD-aware swizzle: bid%8 = XCD; give each XCD a contiguous batch range ----
    const int nper = gridDim.x >> 3;               // 256 blocks per XCD
    const int bid  = blockIdx.x;
    const int swz  = (bid & 7) * nper + (bid >> 3);
    const int b    = swz / QB;
    const int q0   = (swz % QB) * TQ;

    const int tid  = threadIdx.x;
    const int wave = tid >> 6;
    const int wr   = wave >> 3;    // 0/1 q-row group
    const int wc   = wave & 7;     // col group
    const int lane = tid & 63;
    const int l15  = lane & 15;
    const int g    = lane >> 4;    // 0..3

    __shared__ _Float16 Pbuf[2][TQ][CPW + PPAD];   // double-buffered P chunks (f16)
    __shared__ float red[16][16];                  // per-wave row partials
    __shared__ float gmax[TQ];
    __shared__ float grs[TQ];                      // reciprocal row sums

    // ---- Q fragments: A[m=l15][k = ks*32 + g*8 + j] ----
    const float* qrow = Q + ((size_t)b * S + (q0 + wr * 16 + l15)) * D;
    half8 qf[4];
#pragma unroll
    for (int ks = 0; ks < 4; ++ks) {
        const int d0 = ks * 32 + g * 8;
        f32x4v a = *(const f32x4v*)(qrow + d0);
        f32x4v c = *(const f32x4v*)(qrow + d0 + 4);
        half8 h;
        h[0]=(_Float16)a[0]; h[1]=(_Float16)a[1]; h[2]=(_Float16)a[2]; h[3]=(_Float16)a[3];
        h[4]=(_Float16)c[0]; h[5]=(_Float16)c[1]; h[6]=(_Float16)c[2]; h[7]=(_Float16)c[3];
        qf[ks] = h;
    }

    // ---- QK^T: wave (wr,wc) -> rows wr*16..+16, cols wc*256..+256 ----
    const float* kbase = K + (size_t)b * S * D;
    f32x4v acc[NT];
#pragma unroll
    for (int t = 0; t < NT; ++t) { acc[t][0]=0.f; acc[t][1]=0.f; acc[t][2]=0.f; acc[t][3]=0.f; }
#pragma unroll
    for (int t = 0; t < NT; ++t) {
        const float* krow = kbase + (size_t)(wc * CPW + t * 16 + l15) * D;
#pragma unroll
        for (int ks = 0; ks < 4; ++ks) {
            const int d0 = ks * 32 + g * 8;
            f32x4v x = *(const f32x4v*)(krow + d0);
            f32x4v y = *(const f32x4v*)(krow + d0 + 4);
            half8 kf;
            kf[0]=(_Float16)x[0]; kf[1]=(_Float16)x[1]; kf[2]=(_Float16)x[2]; kf[3]=(_Float16)x[3];
            kf[4]=(_Float16)y[0]; kf[5]=(_Float16)y[1]; kf[6]=(_Float16)y[2]; kf[7]=(_Float16)y[3];
            acc[t] = __builtin_amdgcn_mfma_f32_16x16x32_f16(qf[ks], kf, acc[t], 0, 0, 0);
        }
    }

    // ---- scale + per-wave row max (butterfly over l15, rows are per-g) ----
    float mx[4];
#pragma unroll
    for (int r = 0; r < 4; ++r) {
        float m = -1e30f;
#pragma unroll
        for (int t = 0; t < NT; ++t) {
            acc[t][r] *= SCALE;
            m = fmaxf(m, acc[t][r]);
        }
#pragma unroll
        for (int off = 1; off < 16; off <<= 1)
            m = fmaxf(m, __shfl_xor(m, off, 64));
        mx[r] = m;
    }
    if (l15 == 0) {
#pragma unroll
        for (int r = 0; r < 4; ++r) red[wave][g * 4 + r] = mx[r];
    }
    __syncthreads();
    if (tid < TQ) {
        const int wr_ = tid >> 4, lr = tid & 15;
        float m = red[wr_ * 8][lr];
#pragma unroll
        for (int w = 1; w < 8; ++w) m = fmaxf(m, red[wr_ * 8 + w][lr]);
        gmax[tid] = m;
    }
    __syncthreads();

    // ---- exp + per-wave row sum ----
    float sm[4];
#pragma unroll
    for (int r = 0; r < 4; ++r) {
        const float gm = gmax[wr * 16 + g * 4 + r];
        float s = 0.0f;
#pragma unroll
        for (int t = 0; t < NT; ++t) {
            float p = __expf(acc[t][r] - gm);
            acc[t][r] = p;
            s += p;
        }
#pragma unroll
        for (int off = 1; off < 16; off <<= 1)
            s += __shfl_xor(s, off, 64);
        sm[r] = s;
    }
    if (l15 == 0) {
#pragma unroll
        for (int r = 0; r < 4; ++r) red[wave][g * 4 + r] = sm[r];
    }
    __syncthreads();
    if (tid < TQ) {
        const int wr_ = tid >> 4, lr = tid & 15;
        float s = 0.0f;
#pragma unroll
        for (int w = 0; w < 8; ++w) s += red[wr_ * 8 + w][lr];
        grs[tid] = 1.0f / s;
    }
    __syncthreads();

    // ---- normalize + global attn write (the 536MB stream) + pack f16 in regs ----
    float rv[4];
#pragma unroll
    for (int r = 0; r < 4; ++r) rv[r] = grs[wr * 16 + g * 4 + r];

    float* oab = Oa + ((size_t)b * S + q0 + wr * 16) * S + wc * CPW;
    half4 ph[NT];
#pragma unroll
    for (int t = 0; t < NT; ++t) {
        const int c = t * 16 + l15;
#pragma unroll
        for (int r = 0; r < 4; ++r) {
            float pn = acc[t][r] * rv[r];
            ph[t][r] = (_Float16)pn;
            oab[(size_t)(g * 4 + r) * S + c] = pn;
        }
    }

    // ---- P.V: each wave owns out tile rows wr*16, dcols wc*16 over FULL k ----
    // chunk cw = score cols [cw*256, +256); producers = the 2 waves with wc==cw,
    // double-buffered: chunk cw+1 written while chunk cw is consumed. 1 barrier/chunk.
    auto write_slice = [&](int bi) {
#pragma unroll
        for (int t = 0; t < NT; ++t) {
            const int c = t * 16 + l15;
#pragma unroll
            for (int r = 0; r < 4; ++r)
                Pbuf[bi][wr * 16 + g * 4 + r][c] = ph[t][r];
        }
    };

    const float* vb0 = V + (size_t)b * S * D + (wc * 16 + l15);
    f32x4v ctx; ctx[0]=0.f; ctx[1]=0.f; ctx[2]=0.f; ctx[3]=0.f;

    if (wc == 0) write_slice(0);
    __syncthreads();

    for (int cw = 0; cw < 8; ++cw) {
        if (wc == cw + 1) write_slice((cw + 1) & 1);
        const _Float16* prow = &Pbuf[cw & 1][wr * 16 + l15][g * 8];
        const float* vb = vb0 + (size_t)(cw * CPW + g * 8) * D;
#pragma unroll
        for (int mf = 0; mf < 8; ++mf) {
            half8 pf = *(const half8*)(prow + mf * 32);   // conflict-free b128
            half8 vf;
#pragma unroll
            for (int j = 0; j < 8; ++j)
                vf[j] = (_Float16)vb[(size_t)(mf * 32 + j) * D];
            ctx = __builtin_amdgcn_mfma_f32_16x16x32_f16(pf, vf, ctx, 0, 0, 0);
        }
        __syncthreads();
    }

    // ---- context write: lane (g,l15) reg r holds ctx[row g*4+r][dcol l15] ----
    float* ocb = Oc + ((size_t)b * S + q0 + wr * 16) * D + (wc * 16 + l15);
#pragma unroll
    for (int r = 0; r < 4; ++r)
        ocb[(size_t)(g * 4 + r) * D] = ctx[r];
}

extern "C" void kernel_launch(void* const* d_in, const int* in_sizes, int n_in,
                              void* d_out, int out_size, void* d_ws, size_t ws_size,
                              hipStream_t stream) {
    const float* q = (const float*)d_in[0];
    const float* k = (const float*)d_in[1];
    const float* v = (const float*)d_in[2];
    const int B = in_sizes[0] / (S * D);   // 32
    float* ctx  = (float*)d_out;
    float* attn = ctx + (size_t)B * S * D;
    dim3 grid(B * QB);                     // 2048 blocks, 1D for XCD swizzle
    attn_fwd<<<grid, dim3(1024), 0, stream>>>(q, k, v, ctx, attn);
}

// Round 2
// 1255.839 us; speedup vs baseline: 1.0547x; 1.0547x over previous
//
#include <hip/hip_runtime.h>

typedef _Float16 half8 __attribute__((ext_vector_type(8)));
typedef _Float16 half4 __attribute__((ext_vector_type(4)));
typedef float    f32x4v __attribute__((ext_vector_type(4)));

constexpr int S   = 2048;    // sequence length
constexpr int D   = 128;     // hidden dim
constexpr int TQ  = 32;      // q rows per block
constexpr int QB  = S / TQ;  // 64 q-blocks per batch
constexpr int CPW = 256;     // score cols per col-wave-group (8 groups)
constexpr int NT  = CPW / 16;   // 16 col tiles per wave in QK^T
constexpr int CK  = 64;         // PV k-chunk
constexpr int NC  = S / CK;     // 32 chunks
constexpr float SCALE = 0.08838834764831845f; // 1/sqrt(128)

// 16 waves = 2 q-row groups (wr) x 8 col groups (wc). 16x16x32 f16 MFMA.
// C/D layout (m89): col = lane&15, row = (lane>>4)*4 + reg.
// QK^T computed TRANSPOSED (A=K, B=Q) so each lane holds one q-row slice:
//   acc[t][r] = score[kcol = wc*256 + t*16 + g*4 + r][qrow = wr*16 + l15]
__launch_bounds__(1024, 4)
__global__ void attn_fwd(const float* __restrict__ Q,
                         const float* __restrict__ K,
                         const float* __restrict__ V,
                         float* __restrict__ Oc,
                         float* __restrict__ Oa)
{
    // XCD-aware swizzle (2048 % 8 == 0 -> bijective)
    const int nper = gridDim.x >> 3;
    const int bid  = blockIdx.x;
    const int swz  = (bid & 7) * nper + (bid >> 3);
    const int b    = swz / QB;
    const int q0   = (swz % QB) * TQ;

    const int tid  = threadIdx.x;
    const int wave = tid >> 6;
    const int wr   = wave >> 3;    // 0/1 q-row group
    const int wc   = wave & 7;     // col group
    const int lane = tid & 63;
    const int l15  = lane & 15;
    const int g    = lane >> 4;    // 0..3

    // XOR-swizzled (group-of-8-halves ^ row&7) -> all accesses 2-way, conflict-free
    __shared__ _Float16 Vlds[2][128][64];  // [dcol][k-local], transposed V chunk, f16
    __shared__ _Float16 Pbuf[2][TQ][64];   // [qrow][k-local], P chunk, f16
    __shared__ float red[16][16];
    __shared__ float gmax[TQ];
    __shared__ float grs[TQ];

    // ---- Q fragments: B[k=g*8+j][n=l15] = Q[qrow=wr*16+l15][d=ks*32+g*8+j] ----
    const float* qrow_p = Q + ((size_t)b * S + (q0 + wr * 16 + l15)) * D;
    half8 qf[4];
#pragma unroll
    for (int ks = 0; ks < 4; ++ks) {
        const int d0 = ks * 32 + g * 8;
        f32x4v x = *(const f32x4v*)(qrow_p + d0);
        f32x4v y = *(const f32x4v*)(qrow_p + d0 + 4);
        half8 h;
        h[0]=(_Float16)x[0]; h[1]=(_Float16)x[1]; h[2]=(_Float16)x[2]; h[3]=(_Float16)x[3];
        h[4]=(_Float16)y[0]; h[5]=(_Float16)y[1]; h[6]=(_Float16)y[2]; h[7]=(_Float16)y[3];
        qf[ks] = h;
    }

    // ---- QK^T transposed: A = K rows (wc*256 + t*16 + l15), B = Q ----
    const float* kbase = K + (size_t)b * S * D;
    f32x4v acc[NT];
#pragma unroll
    for (int t = 0; t < NT; ++t) { acc[t][0]=0.f; acc[t][1]=0.f; acc[t][2]=0.f; acc[t][3]=0.f; }
#pragma unroll
    for (int t = 0; t < NT; ++t) {
        const float* krow = kbase + (size_t)(wc * CPW + t * 16 + l15) * D;
#pragma unroll
        for (int ks = 0; ks < 4; ++ks) {
            const int d0 = ks * 32 + g * 8;
            f32x4v x = *(const f32x4v*)(krow + d0);
            f32x4v y = *(const f32x4v*)(krow + d0 + 4);
            half8 kf;
            kf[0]=(_Float16)x[0]; kf[1]=(_Float16)x[1]; kf[2]=(_Float16)x[2]; kf[3]=(_Float16)x[3];
            kf[4]=(_Float16)y[0]; kf[5]=(_Float16)y[1]; kf[6]=(_Float16)y[2]; kf[7]=(_Float16)y[3];
            acc[t] = __builtin_amdgcn_mfma_f32_16x16x32_f16(kf, qf[ks], acc[t], 0, 0, 0);
        }
    }

    // ---- softmax: every lane's 64 values belong to q-row wr*16+l15 ----
    float m = -1e30f;
#pragma unroll
    for (int t = 0; t < NT; ++t) {
        acc[t] *= SCALE;
#pragma unroll
        for (int r = 0; r < 4; ++r) m = fmaxf(m, acc[t][r]);
    }
    m = fmaxf(m, __shfl_xor(m, 16, 64));
    m = fmaxf(m, __shfl_xor(m, 32, 64));
    if (lane < 16) red[wave][l15] = m;
    __syncthreads();
    if (tid < TQ) {
        const int wr_ = tid >> 4, lr = tid & 15;
        float mm = red[wr_ * 8][lr];
#pragma unroll
        for (int w = 1; w < 8; ++w) mm = fmaxf(mm, red[wr_ * 8 + w][lr]);
        gmax[tid] = mm;
    }
    __syncthreads();

    const float gm = gmax[wr * 16 + l15];
    float sum = 0.0f;
#pragma unroll
    for (int t = 0; t < NT; ++t) {
#pragma unroll
        for (int r = 0; r < 4; ++r) {
            float p = __expf(acc[t][r] - gm);
            acc[t][r] = p;
            sum += p;
        }
    }
    sum += __shfl_xor(sum, 16, 64);
    sum += __shfl_xor(sum, 32, 64);
    if (lane < 16) red[wave][l15] = sum;
    __syncthreads();
    if (tid < TQ) {
        const int wr_ = tid >> 4, lr = tid & 15;
        float ss = 0.0f;
#pragma unroll
        for (int w = 0; w < 8; ++w) ss += red[wr_ * 8 + w][lr];
        grs[tid] = 1.0f / ss;
    }
    __syncthreads();

    // ---- normalize: float4 Oa stores + f16 pack into regs ----
    const float rv = grs[wr * 16 + l15];
    float* oar = Oa + ((size_t)b * S + q0 + wr * 16 + l15) * S + wc * CPW + g * 4;
    half4 ph[NT];
#pragma unroll
    for (int t = 0; t < NT; ++t) {
        f32x4v pn = acc[t] * rv;
        *(f32x4v*)(oar + t * 16) = pn;
        half4 h; h[0]=(_Float16)pn[0]; h[1]=(_Float16)pn[1]; h[2]=(_Float16)pn[2]; h[3]=(_Float16)pn[3];
        ph[t] = h;
    }

    // ---- PV: V staged through LDS (transposed, swizzled), double-buffered ----
    const int sd  = tid & 127;          // staged d-column
    const int skq = tid >> 7;           // staged k-quad (8 rows)
    const float* vsrc = V + (size_t)b * S * D + sd;

    float vr[2][8];                     // depth-2 prefetch regs (compile-time indexed)
    f32x4v ctx; ctx[0]=0.f; ctx[1]=0.f; ctx[2]=0.f; ctx[3]=0.f;
    const int prow = wr * 16 + l15;
    const int vrow = wc * 16 + l15;

    auto stage_load = [&](float* dst, int cc) {
#pragma unroll
        for (int i = 0; i < 8; ++i)
            dst[i] = vsrc[(size_t)(cc * CK + skq * 8 + i) * D];
    };
    auto stage_write = [&](int cc, const float* src) {
        half8 vh;
#pragma unroll
        for (int i = 0; i < 8; ++i) vh[i] = (_Float16)src[i];
        *(half8*)&Vlds[cc & 1][sd][(skq ^ (sd & 7)) << 3] = vh;
    };

    // prologue: chunk 0 staged + P chunk 0; chunk 1 loads in flight
    stage_load(vr[0], 0);
    stage_write(0, vr[0]);
    if (wc == 0) {
#pragma unroll
        for (int tt = 0; tt < 4; ++tt) {
            const int gi = tt * 2 + (g >> 1);
            *(half4*)&Pbuf[0][prow][((gi ^ (prow & 7)) << 3) + ((g & 1) << 2)] = ph[tt];
        }
    }
    stage_load(vr[1], 1);
    __syncthreads();

#pragma unroll
    for (int c = 0; c < NC; ++c) {
        if (c + 1 < NC) {
            stage_write(c + 1, vr[(c + 1) & 1]);
            if (wc == ((c + 1) >> 2)) {
                const int sub = (c + 1) & 3;
#pragma unroll
                for (int tt = 0; tt < 4; ++tt) {
                    const int gi = tt * 2 + (g >> 1);
                    *(half4*)&Pbuf[(c + 1) & 1][prow][((gi ^ (prow & 7)) << 3) + ((g & 1) << 2)]
                        = ph[sub * 4 + tt];
                }
            }
        }
        if (c + 2 < NC) stage_load(vr[c & 1], c + 2);
#pragma unroll
        for (int mf = 0; mf < 2; ++mf) {
            const int gi = mf * 4 + g;
            half8 pf = *(const half8*)&Pbuf[c & 1][prow][((gi ^ (prow & 7)) << 3)];
            half8 vf = *(const half8*)&Vlds[c & 1][vrow][((gi ^ (vrow & 7)) << 3)];
            ctx = __builtin_amdgcn_mfma_f32_16x16x32_f16(pf, vf, ctx, 0, 0, 0);
        }
        __syncthreads();
    }

    // ---- context write: ctx[r] = C[qrow = wr*16 + g*4 + r][dcol = wc*16 + l15] ----
    float* ocb = Oc + ((size_t)b * S + q0 + wr * 16) * D + (wc * 16 + l15);
#pragma unroll
    for (int r = 0; r < 4; ++r)
        ocb[(size_t)(g * 4 + r) * D] = ctx[r];
}

extern "C" void kernel_launch(void* const* d_in, const int* in_sizes, int n_in,
                              void* d_out, int out_size, void* d_ws, size_t ws_size,
                              hipStream_t stream) {
    const float* q = (const float*)d_in[0];
    const float* k = (const float*)d_in[1];
    const float* v = (const float*)d_in[2];
    const int B = in_sizes[0] / (S * D);   // 32
    float* ctx  = (float*)d_out;
    float* attn = ctx + (size_t)B * S * D;
    dim3 grid(B * QB);                     // 2048 blocks
    attn_fwd<<<grid, dim3(1024), 0, stream>>>(q, k, v, ctx, attn);
}